// Round 11
// baseline (93.695 us; speedup 1.0000x reference)
//
#include <hip/hip_runtime.h>

#define BATCH   32
#define SEQ     2048
#define MDIM    128
#define LBAS    64
#define NW      2041        // SEQ - RANK + 1
#define TW      32          // windows per tile
#define NTILE   2           // tiles per block -> 64 windows/block
#define APAD    136         // bf16 elems per sA row

typedef __attribute__((ext_vector_type(8))) short  short8;
typedef __attribute__((ext_vector_type(4))) float  float4v;

__device__ __forceinline__ unsigned short f2bf(float f) {   // RNE (prep only)
    unsigned int u = __float_as_uint(f);
    return (unsigned short)((u + 0x7FFFu + ((u >> 16) & 1u)) >> 16);
}

// fast pack: fp32x4 -> bf16x4, round-half-up via +0x8000, v_perm high halves
__device__ __forceinline__ void store_sum_bf16x4(unsigned short* p, float4v a) {
    unsigned int ux = __float_as_uint(a.x) + 0x8000u;
    unsigned int uy = __float_as_uint(a.y) + 0x8000u;
    unsigned int uz = __float_as_uint(a.z) + 0x8000u;
    unsigned int uw = __float_as_uint(a.w) + 0x8000u;
    unsigned int lo = __builtin_amdgcn_perm(uy, ux, 0x07060302u);
    unsigned int hi = __builtin_amdgcn_perm(uw, uz, 0x07060302u);
    *reinterpret_cast<unsigned long long*>(p) = ((unsigned long long)hi << 32) | lo;
}

// ---------------------------------------------------------------------------
// Prep: Mb = bf16(M * 0.125) frag-linear (1/8 window-mean folded in);
//       nk[k][n] = Acoeff[n][k] * Bbasis[k][n]
// ---------------------------------------------------------------------------
__global__ __launch_bounds__(256)
void ndd_prep(const float* __restrict__ Mmat,
              const float* __restrict__ Acoeff,
              const float* __restrict__ Bbasis,
              unsigned short* __restrict__ Mb,
              float* __restrict__ nk)
{
    const int gid = blockIdx.x * 256 + threadIdx.x;
    if (gid < 2048) {                    // 128 rows x 16 k-chunks
        const int n = gid >> 4;
        const int c = gid & 15;
        const float* src = Mmat + n * MDIM + c * 8;
        short8 v;
        #pragma unroll
        for (int j = 0; j < 8; ++j) v[j] = (short)f2bf(src[j] * 0.125f);
        *reinterpret_cast<short8*>(Mb + ((size_t)(c * MDIM + n)) * 8) = v;
    } else if (gid < 2048 + 8192) {      // 64 x 128 nk table
        const int e = gid - 2048;
        const int k = e >> 7;
        const int n = e & 127;
        nk[k * MDIM + n] = Acoeff[n * LBAS + k] * Bbasis[k * MDIM + n];
    }
}

// ---------------------------------------------------------------------------
// Main: 1024 blocks x 2 tiles of 32 windows (3 blocks/CU resident -> block
// generations overlap prologue/tail). Double-buffered raw staging, raw
// s_barrier + per-wave vmcnt(5)/(0) (R7/R9/R10-proven). Phase 2 on waves
// 0-1: 8-window running sums, perm-pack. sA holds SUMS (1/8 in Mb).
// Fused reduction: one atomicAdd per block.
// ---------------------------------------------------------------------------
__global__ __launch_bounds__(256, 2)
void ndd_main(const float* __restrict__ x,            // [32][2048][128]
              const unsigned short* __restrict__ Mb,  // bf16(M/8) frag-linear
              const float* __restrict__ nk,           // [64][128]
              float* __restrict__ out)
{
    __shared__ __align__(16) float sRaw[2][20 * 256];             // 2 x 20 KB
    __shared__ __align__(16) unsigned short sA[TW * APAD];        // 8.7 KB
    __shared__ float sred[4];

    const int tid  = threadIdx.x;
    const int lane = tid & 63;
    const int wave = tid >> 6;
    const int b    = blockIdx.x >> 5;          // batch 0..31
    const int base = (blockIdx.x & 31) * 64;   // window base (mult of 64)
    const float* xb = x + (size_t)b * SEQ * MDIM;

    const int l15 = lane & 15;
    const int q   = lane >> 4;
    const int nb  = wave * 32;                 // this wave's n-columns

    // ---- hoist B-fragments (coalesced bf16 from prep output) ----
    short8 bfr[4][2];
    #pragma unroll
    for (int kk = 0; kk < 4; ++kk)
        #pragma unroll
        for (int nj = 0; nj < 2; ++nj)
            bfr[kk][nj] = *reinterpret_cast<const short8*>(
                Mb + ((size_t)((kk * 4 + q) * MDIM + nb + nj * 16 + l15)) * 8);

    // ---- hoist nk: k = j*32 + wi*16 + q*4 + r (base is mult of 64) ----
    float nkreg[2][2][2][4];
    #pragma unroll
    for (int p = 0; p < 2; ++p)
        #pragma unroll
        for (int wi = 0; wi < 2; ++wi)
            #pragma unroll
            for (int nj = 0; nj < 2; ++nj)
                #pragma unroll
                for (int r = 0; r < 4; ++r)
                    nkreg[p][wi][nj][r] =
                        nk[(p * 32 + wi * 16 + q * 4 + r) * MDIM + nb + nj * 16 + l15];

    // ---- DMA: 40 rows (20 x 1KB chunks) per tile, 5 chunks per wave ----
    auto issue = [&](int j) {
        const int W0r = base + j * TW;
        #pragma unroll
        for (int i = 0; i < 5; ++i) {
            const int c = wave * 5 + i;            // chunk 0..19
            int r0 = W0r + 2 * c;
            r0 = r0 > 2046 ? 2046 : r0;            // real rows only
            const float* g = xb + (size_t)r0 * MDIM + lane * 4;
            __builtin_amdgcn_global_load_lds(
                (const __attribute__((address_space(1))) void*)g,
                (__attribute__((address_space(3))) void*)&sRaw[j & 1][c * 256],
                16, 0, 0);
        }
    };
    issue(0);
    issue(1);

    float local = 0.f;

    #pragma unroll
    for (int j = 0; j < NTILE; ++j) {
        // wait own 5 chunks of tile j (tile j+1's 5 newest may still fly)
        __builtin_amdgcn_sched_barrier(0);
        if (j == NTILE - 1) __builtin_amdgcn_s_waitcnt(0x0F70);  // vmcnt(0)
        else                __builtin_amdgcn_s_waitcnt(0x0F75);  // vmcnt(5)
        asm volatile("s_barrier" ::: "memory");
        __builtin_amdgcn_sched_barrier(0);

        // ---- phase 2 (waves 0-1): 8-window running sums -> bf16 sA ----
        if (tid < 128) {
            const int m4  = tid & 31;
            const int seg = tid >> 5;              // 0..3 -> windows seg*8..+7
            const float4v* R = reinterpret_cast<const float4v*>(&sRaw[j & 1][0]);
            float4v rows[15];
            #pragma unroll
            for (int i = 0; i < 15; ++i)
                rows[i] = R[(seg * 8 + i) * 32 + m4];
            float4v acc = ((rows[0] + rows[1]) + (rows[2] + rows[3])) +
                          ((rows[4] + rows[5]) + (rows[6] + rows[7]));
            store_sum_bf16x4(&sA[(seg * 8) * APAD + m4 * 4], acc);
            #pragma unroll
            for (int t = 1; t < 8; ++t) {
                acc += rows[7 + t] - rows[t - 1];
                store_sum_bf16x4(&sA[(seg * 8 + t) * APAD + m4 * 4], acc);
            }
        }

        __builtin_amdgcn_sched_barrier(0);
        __builtin_amdgcn_s_waitcnt(0xC07F);        // lgkmcnt(0) only
        asm volatile("s_barrier" ::: "memory");
        __builtin_amdgcn_sched_barrier(0);

        // ---- phase 3: MFMA C[w][n] = sum_m aggsum[w][m] * (M/8)[n][m] ----
        float4v accf[2][2];
        #pragma unroll
        for (int wi = 0; wi < 2; ++wi)
            #pragma unroll
            for (int nj = 0; nj < 2; ++nj)
                accf[wi][nj] = (float4v){0.f, 0.f, 0.f, 0.f};
        #pragma unroll
        for (int kk = 0; kk < 4; ++kk) {
            short8 af[2];
            #pragma unroll
            for (int wi = 0; wi < 2; ++wi)
                af[wi] = *reinterpret_cast<const short8*>(
                    &sA[(wi * 16 + l15) * APAD + kk * 32 + q * 8]);
            #pragma unroll
            for (int wi = 0; wi < 2; ++wi)
                #pragma unroll
                for (int nj = 0; nj < 2; ++nj)
                    accf[wi][nj] = __builtin_amdgcn_mfma_f32_16x16x32_bf16(
                        af[wi], bfr[kk][nj], accf[wi][nj], 0, 0, 0);
        }

        // ---- epilogue: (C - nk)^2, masked ----
        #pragma unroll
        for (int wi = 0; wi < 2; ++wi) {
            #pragma unroll
            for (int nj = 0; nj < 2; ++nj) {
                #pragma unroll
                for (int r = 0; r < 4; ++r) {
                    const int w = base + j * TW + wi * 16 + q * 4 + r;
                    if (w < NW) {
                        const float d = accf[wi][nj][r] - nkreg[j][wi][nj][r];
                        local += d * d;
                    }
                }
            }
        }
    }

    // ---- block reduce -> one atomic (reduce kernel fused away) ----
    #pragma unroll
    for (int off = 32; off > 0; off >>= 1)
        local += __shfl_down(local, off, 64);
    if (lane == 0) sred[wave] = local;
    __syncthreads();
    if (tid == 0)
        atomicAdd(out, ((sred[0] + sred[1]) + (sred[2] + sred[3]))
                           * (1.0f / 8359936.0f));   // 1/(32*2041*128)
}

extern "C" void kernel_launch(void* const* d_in, const int* in_sizes, int n_in,
                              void* d_out, int out_size, void* d_ws, size_t ws_size,
                              hipStream_t stream) {
    const float* x     = (const float*)d_in[0];
    const float* Mmat  = (const float*)d_in[1];
    const float* Acoef = (const float*)d_in[2];
    const float* Bbas  = (const float*)d_in[3];
    float* out         = (float*)d_out;

    unsigned short* Mb = (unsigned short*)d_ws;             // 32 KB bf16
    float* nkp         = (float*)((char*)d_ws + 32768);     // 32 KB fp32

    hipMemsetAsync(out, 0, sizeof(float), stream);
    ndd_prep<<<40, 256, 0, stream>>>(Mmat, Acoef, Bbas, Mb, nkp);
    ndd_main<<<1024, 256, 0, stream>>>(x, Mb, nkp, out);
}

// Round 12
// 82.791 us; speedup vs baseline: 1.1317x; 1.1317x over previous
//
#include <hip/hip_runtime.h>

#define BATCH   32
#define SEQ     2048
#define MDIM    128
#define LBAS    64
#define NW      2041        // SEQ - RANK + 1
#define TW      16          // windows per tile
#define NTILE   8           // tiles per block -> 128 windows/block
#define APAD    136         // bf16 elems per sA row

typedef __attribute__((ext_vector_type(8))) short  short8;
typedef __attribute__((ext_vector_type(4))) float  float4v;

__device__ __forceinline__ unsigned short f2bf(float f) {
    unsigned int u = __float_as_uint(f);
    return (unsigned short)((u + 0x7FFFu + ((u >> 16) & 1u)) >> 16);
}
__device__ __forceinline__ void store_bf16x4(unsigned short* p, float4v a) {
    unsigned int lo = (unsigned)f2bf(a.x) | ((unsigned)f2bf(a.y) << 16);
    unsigned int hi = (unsigned)f2bf(a.z) | ((unsigned)f2bf(a.w) << 16);
    *reinterpret_cast<unsigned long long*>(p) = ((unsigned long long)hi << 32) | lo;
}

// ---------------------------------------------------------------------------
// Prep: M -> bf16 B-fragment-linear Mb[(k>>3)*128+n][j];
//       nkT[n][k] = Acoeff[n][k] * Bbasis[k][n]   (TRANSPOSED: main loads f4)
// ---------------------------------------------------------------------------
__global__ __launch_bounds__(256)
void ndd_prep(const float* __restrict__ Mmat,
              const float* __restrict__ Acoeff,
              const float* __restrict__ Bbasis,
              unsigned short* __restrict__ Mb,
              float* __restrict__ nkT)
{
    const int gid = blockIdx.x * 256 + threadIdx.x;
    if (gid < 2048) {                    // 128 rows x 16 k-chunks
        const int n = gid >> 4;
        const int c = gid & 15;
        const float* src = Mmat + n * MDIM + c * 8;
        short8 v;
        #pragma unroll
        for (int j = 0; j < 8; ++j) v[j] = (short)f2bf(src[j]);
        *reinterpret_cast<short8*>(Mb + ((size_t)(c * MDIM + n)) * 8) = v;
    } else if (gid < 2048 + 8192) {      // nkT: [128][64]
        const int e = gid - 2048;
        const int n = e >> 6;
        const int k = e & 63;
        nkT[e] = Acoeff[e] * Bbasis[k * MDIM + n];   // Acoeff is [n][k] too
    }
}

// ---------------------------------------------------------------------------
// Main (R7-proven structure, best measured 83.3 us total):
// 512 persistent blocks x 8 tiles of 16 windows. 3-buffer raw staging,
// depth-2 global_load_lds prefetch, raw s_barrier (inline asm, no vmcnt(0)
// drain) + manual per-wave vmcnt(3): steady state keeps 6 chunks/wave in
// flight. B-fragments and nk tile-invariant -> register-hoisted per block
// (nk now via 8 coalesced float4 loads from nkT).
// ---------------------------------------------------------------------------
__global__ __launch_bounds__(256, 2)
void ndd_main(const float* __restrict__ x,            // [32][2048][128]
              const unsigned short* __restrict__ Mb,  // bf16 frag-linear
              const float* __restrict__ nkT,          // [128][64]
              float* __restrict__ partial)            // [512]
{
    __shared__ __align__(16) float sRaw[3][12 * 256];             // 3 x 12 KB
    __shared__ __align__(16) unsigned short sA[TW * APAD];        // 4.25 KB
    __shared__ float sred[4];

    const int tid  = threadIdx.x;
    const int lane = tid & 63;
    const int wave = tid >> 6;
    const int b    = blockIdx.x >> 4;          // batch
    const int base = (blockIdx.x & 15) * 128;  // window base (mult of 64)
    const float* xb = x + (size_t)b * SEQ * MDIM;

    const int l15 = lane & 15;
    const int q   = lane >> 4;
    const int nb  = wave * 32;                 // this wave's n-columns

    // ---- hoist B-fragments (tile-invariant): 8 frags = 32 VGPRs ----
    short8 bfr[4][2];
    #pragma unroll
    for (int kk = 0; kk < 4; ++kk)
        #pragma unroll
        for (int nj = 0; nj < 2; ++nj)
            bfr[kk][nj] = *reinterpret_cast<const short8*>(
                Mb + ((size_t)((kk * 4 + q) * MDIM + nb + nj * 16 + l15)) * 8);

    // ---- hoist nk via nkT: k = p*16 + q*4 + r -> one float4 per (p,nj) ----
    float4v nkreg[4][2];
    #pragma unroll
    for (int p = 0; p < 4; ++p)
        #pragma unroll
        for (int nj = 0; nj < 2; ++nj)
            nkreg[p][nj] = *reinterpret_cast<const float4v*>(
                nkT + (size_t)(nb + nj * 16 + l15) * LBAS + p * 16 + q * 4);

    // ---- DMA: 12 chunks (24 rows) per tile, 3 chunks per wave ----
    auto issue = [&](int j) {
        const int W0r = base + j * TW;
        #pragma unroll
        for (int i = 0; i < 3; ++i) {
            const int c = wave * 3 + i;            // chunk 0..11
            int r0 = W0r + 2 * c;
            r0 = r0 > 2046 ? 2046 : r0;            // real rows only
            const float* g = xb + (size_t)r0 * MDIM + lane * 4;
            __builtin_amdgcn_global_load_lds(
                (const __attribute__((address_space(1))) void*)g,
                (__attribute__((address_space(3))) void*)&sRaw[j % 3][c * 256],
                16, 0, 0);
        }
    };
    issue(0);
    issue(1);

    float local = 0.f;

    #pragma unroll
    for (int j = 0; j < NTILE; ++j) {
        // wait: tile j's 3 chunks done (tile j+1's 3 may still fly)
        __builtin_amdgcn_sched_barrier(0);
        if (j == NTILE - 1) __builtin_amdgcn_s_waitcnt(0x0F70);  // vmcnt(0)
        else                __builtin_amdgcn_s_waitcnt(0x0F73);  // vmcnt(3)
        asm volatile("s_barrier" ::: "memory");
        __builtin_amdgcn_sched_barrier(0);

        // ---- phase 2: window means from raw[j%3] -> bf16 sA ----
        {
            const int m4 = tid & 31;
            const int wg = tid >> 5;               // windows wg*2, wg*2+1
            const float4v* R = reinterpret_cast<const float4v*>(&sRaw[j % 3][0]);
            float4v rows[9];
            #pragma unroll
            for (int i = 0; i < 9; ++i) rows[i] = R[(wg * 2 + i) * 32 + m4];
            float4v acc = ((rows[0] + rows[1]) + (rows[2] + rows[3])) +
                          ((rows[4] + rows[5]) + (rows[6] + rows[7]));
            store_bf16x4(&sA[(wg * 2) * APAD + m4 * 4], acc * 0.125f);
            acc += rows[8] - rows[0];
            store_bf16x4(&sA[(wg * 2 + 1) * APAD + m4 * 4], acc * 0.125f);
        }

        __builtin_amdgcn_sched_barrier(0);
        __builtin_amdgcn_s_waitcnt(0xC07F);        // lgkmcnt(0) only
        asm volatile("s_barrier" ::: "memory");
        __builtin_amdgcn_sched_barrier(0);

        // ---- depth-2 prefetch: tile j+2 into buffer (j+2)%3 ----
        if (j + 2 < NTILE) issue(j + 2);

        // ---- phase 3: MFMA C[w][n], pure LDS + registers ----
        float4v accf[2] = {(float4v){0.f,0.f,0.f,0.f}, (float4v){0.f,0.f,0.f,0.f}};
        #pragma unroll
        for (int kk = 0; kk < 4; ++kk) {
            const short8 af = *reinterpret_cast<const short8*>(
                &sA[l15 * APAD + kk * 32 + q * 8]);
            #pragma unroll
            for (int nj = 0; nj < 2; ++nj)
                accf[nj] = __builtin_amdgcn_mfma_f32_16x16x32_bf16(
                    af, bfr[kk][nj], accf[nj], 0, 0, 0);
        }

        // ---- epilogue: (C - nk)^2, masked ----
        const int p = j & 3;
        #pragma unroll
        for (int nj = 0; nj < 2; ++nj) {
            #pragma unroll
            for (int r = 0; r < 4; ++r) {
                const int w = base + j * TW + q * 4 + r;
                if (w < NW) {
                    const float d = accf[nj][r] - nkreg[p][nj][r];
                    local += d * d;
                }
            }
        }
    }

    // ---- block reduce -> one partial ----
    #pragma unroll
    for (int off = 32; off > 0; off >>= 1)
        local += __shfl_down(local, off, 64);
    if (lane == 0) sred[wave] = local;
    __syncthreads();
    if (tid == 0)
        partial[blockIdx.x] = (sred[0] + sred[1]) + (sred[2] + sred[3]);
}

// ---------------------------------------------------------------------------
// Final reduce: 512 partials -> scalar D
// ---------------------------------------------------------------------------
__global__ __launch_bounds__(256)
void ndd_reduce(const float* __restrict__ partial, float* __restrict__ out)
{
    __shared__ float sred[4];
    float s = partial[threadIdx.x] + partial[threadIdx.x + 256];
    #pragma unroll
    for (int off = 32; off > 0; off >>= 1) s += __shfl_down(s, off, 64);
    if ((threadIdx.x & 63) == 0) sred[threadIdx.x >> 6] = s;
    __syncthreads();
    if (threadIdx.x == 0)
        out[0] = ((sred[0] + sred[1]) + (sred[2] + sred[3])) * (1.0f / 8359936.0f);
}

extern "C" void kernel_launch(void* const* d_in, const int* in_sizes, int n_in,
                              void* d_out, int out_size, void* d_ws, size_t ws_size,
                              hipStream_t stream) {
    const float* x     = (const float*)d_in[0];
    const float* Mmat  = (const float*)d_in[1];
    const float* Acoef = (const float*)d_in[2];
    const float* Bbas  = (const float*)d_in[3];
    float* out         = (float*)d_out;

    unsigned short* Mb = (unsigned short*)d_ws;             // 32 KB bf16
    float* nkTp        = (float*)((char*)d_ws + 32768);     // 32 KB fp32
    float* part        = (float*)((char*)d_ws + 65536);     // 2 KB partials

    ndd_prep<<<40, 256, 0, stream>>>(Mmat, Acoef, Bbas, Mb, nkTp);
    ndd_main<<<512, 256, 0, stream>>>(x, Mb, nkTp, part);
    ndd_reduce<<<1, 256, 0, stream>>>(part, out);
}